// Round 10
// baseline (68.073 us; speedup 1.0000x reference)
//
#include <hip/hip_runtime.h>
#include <hip/hip_bf16.h>
#include <stdint.h>

#define NROWS 4096
#define CDIM  512
#define TOPK  5
#define BMJ   128   // prob2 (j) rows per block
#define BNI   256   // prob1 (i) rows per block
#define BK    32
#define NKT   16    // CDIM / BK
#define NBLK  512   // gemm grid

typedef __bf16 bf16x8 __attribute__((ext_vector_type(8)));
typedef float  f32x4  __attribute__((ext_vector_type(4)));
typedef unsigned long long u64;

// slot swizzle: 16-lane b128 fragment reads spread 2x over all 8 bank groups (free)
__device__ __forceinline__ int swz(int row) { return (row ^ (row >> 2)) & 3; }

// ---------------- kernel A: prep = bf16 convert (K-tiled + swizzled) + top-5 keys ----
__global__ __launch_bounds__(256) void
prep_kernel(const float* __restrict__ p1, const float* __restrict__ p2,
            const float* __restrict__ feat1,
            __bf16* __restrict__ o1, __bf16* __restrict__ o2,
            u64* __restrict__ keys, unsigned* __restrict__ counter) {
  const int bid = blockIdx.x, tid = threadIdx.x;
  if (bid == 0 && tid == 0) *counter = 0;   // for gemm's last-block finalize
  if (bid < 2048) {
    const int arr = bid >> 10;            // 0: p1->o1, 1: p2->o2
    const int b2  = bid & 1023;
    const int kt  = b2 >> 6;
    const int c   = (b2 & 63) * 256 + tid;  // row*4 + slot
    const int row = c >> 2;
    const int s   = c & 3;
    const float* src = (arr ? p2 : p1) + (size_t)row * CDIM + kt * 32 + s * 8;
    __bf16*      dst = (arr ? o2 : o1) + ((size_t)kt * NROWS + row) * 32 + ((s ^ swz(row)) * 8);
    const float4 a = *(const float4*)src;
    const float4 b = *(const float4*)(src + 4);
    bf16x8 v;
    v[0]=(__bf16)a.x; v[1]=(__bf16)a.y; v[2]=(__bf16)a.z; v[3]=(__bf16)a.w;
    v[4]=(__bf16)b.x; v[5]=(__bf16)b.y; v[6]=(__bf16)b.z; v[7]=(__bf16)b.w;
    *(bf16x8*)dst = v;                     // plain store: dirty L2 -> kernel-end flush to L3
  } else {
    const int row = (bid - 2048) * 4 + (tid >> 6);
    const int l   = tid & 63;
    const float* r = feat1 + (size_t)row * CDIM;
    float v[8];
    const float4 a = *(const float4*)(r + l * 8);
    const float4 b = *(const float4*)(r + l * 8 + 4);
    v[0]=a.x; v[1]=a.y; v[2]=a.z; v[3]=a.w;
    v[4]=b.x; v[5]=b.y; v[6]=b.z; v[7]=b.w;

    int sel[TOPK];
#pragma unroll
    for (int s = 0; s < TOPK; ++s) {
      float bv = -__builtin_inff();
      int   bi = 0x7fffffff;
#pragma unroll
      for (int t = 0; t < 8; ++t)
        if (v[t] > bv) { bv = v[t]; bi = l * 8 + t; }   // strict > : smallest idx on tie
#pragma unroll
      for (int off = 32; off > 0; off >>= 1) {
        float ov = __shfl_xor(bv, off);
        int   oi = __shfl_xor(bi, off);
        if (ov > bv || (ov == bv && oi < bi)) { bv = ov; bi = oi; }
      }
      sel[s] = bi;
      const int loc = bi - l * 8;
      if (loc >= 0 && loc < 8) v[loc] = -__builtin_inff();
    }
#define CSWAP(x, y) { int mn = min(sel[x], sel[y]); int mx = max(sel[x], sel[y]); sel[x] = mn; sel[y] = mx; }
    CSWAP(0,1) CSWAP(3,4) CSWAP(2,4) CSWAP(2,3) CSWAP(1,4)
    CSWAP(0,3) CSWAP(0,2) CSWAP(1,3) CSWAP(1,2)
#undef CSWAP
    if (l == 0) {
      keys[row] = (u64)sel[0] | ((u64)sel[1] << 9) | ((u64)sel[2] << 18)
                | ((u64)sel[3] << 27) | ((u64)sel[4] << 36);
    }
  }
}

// ---------------- kernel B: GEMM + BCE + L2-warming + last-block finalize ----------------
// R4 structure: 128(j) x 256(i) tile, 512 thr = 8 waves (2x4), per-wave 64x64 =
// acc[4][4]. 3-slot LDS rotation (74 KiB -> 2 blocks/CU), depth-2 counted vmcnt(3).
// NEW: warming pre-pass pulls the block's full panels (384 KB) into the local XCD L2
// via global_load_lds into a dummy scratch, so the K-loop runs L2-hot on sweep 1.
__global__ __launch_bounds__(512, 4) void
gemm_loss_kernel(const __bf16* __restrict__ o1k,   // prob1 (i), K-tiled [kt][row][32]
                 const __bf16* __restrict__ o2k,   // prob2 (j), K-tiled
                 const u64* __restrict__ keys,
                 float* __restrict__ partials,
                 unsigned* __restrict__ counter,
                 float* __restrict__ out) {
  __shared__ __bf16 smA[3][BMJ * BK];   // 3 x 8 KB  (prob2 / j)
  __shared__ __bf16 smB[3][BNI * BK];   // 3 x 16 KB (prob1 / i)
  __shared__ float  red[512];           // epilogue reduce; doubles as warming scratch
  __shared__ int    lastflag;

  const int tid = threadIdx.x;
  const int l   = tid & 63, w = tid >> 6;
  const int wr  = w >> 2,  wc = w & 3;     // j-half, i-quarter
  const int lr  = l & 15,  kq = l >> 4;

  const int bid = blockIdx.x;
  const int x   = bid & 7, v = bid >> 3;   // XCD-chunked swizzle
  const int jt  = (x & 3) * 8 + (v & 7);
  const int it  = (x >> 2) * 8 + (v >> 3);
  const int jb  = jt * BMJ, ib = it * BNI;

  f32x4 acc[4][4] = {};

  const __bf16* gA0 = o2k + (size_t)jb * 32;
  const __bf16* gB0 = o1k + (size_t)ib * 32;

  // ---- L2 warming: 48 loads/thread covering the whole A+B panel, dumped into red ----
  {
    __attribute__((address_space(3))) unsigned int* dummy =
        (__attribute__((address_space(3))) unsigned int*)(void*)&red[0];
#pragma unroll
    for (int kt = 0; kt < NKT; ++kt) {
      const size_t ko = (size_t)kt * NROWS * 32;
      __builtin_amdgcn_global_load_lds(
          (const __attribute__((address_space(1))) unsigned int*)(const void*)(gA0 + ko + tid * 8),
          dummy, 16, 0, 0);
#pragma unroll
      for (int h = 0; h < 2; ++h)
        __builtin_amdgcn_global_load_lds(
            (const __attribute__((address_space(1))) unsigned int*)(const void*)(gB0 + ko + (h * 512 + tid) * 8),
            dummy, 16, 0, 0);
    }
  }

  auto stage = [&](int slot, int kt) {
    const size_t ko = (size_t)kt * NROWS * 32;
    __builtin_amdgcn_global_load_lds(
        (const __attribute__((address_space(1))) unsigned int*)(const void*)(gA0 + ko + tid * 8),
        (__attribute__((address_space(3))) unsigned int*)(void*)&smA[slot][w * 512], 16, 0, 0);
#pragma unroll
    for (int i = 0; i < 2; ++i) {
      __builtin_amdgcn_global_load_lds(
          (const __attribute__((address_space(1))) unsigned int*)(const void*)(gB0 + ko + (i * 512 + tid) * 8),
          (__attribute__((address_space(3))) unsigned int*)(void*)&smB[slot][i * 4096 + w * 512], 16, 0, 0);
    }
  };

  auto compute = [&](int slot) {
    bf16x8 af[4], bfr[4];
#pragma unroll
    for (int m = 0; m < 4; ++m) {
      const int r = wr * 64 + m * 16 + lr;           // 0..127
      af[m] = *(const bf16x8*)&smA[slot][r * 32 + (kq ^ swz(r)) * 8];
    }
#pragma unroll
    for (int n = 0; n < 4; ++n) {
      const int r = wc * 64 + n * 16 + lr;           // 0..255
      bfr[n] = *(const bf16x8*)&smB[slot][r * 32 + (kq ^ swz(r)) * 8];
    }
    __builtin_amdgcn_s_setprio(1);
#pragma unroll
    for (int m = 0; m < 4; ++m)
#pragma unroll
      for (int n = 0; n < 4; ++n)
        acc[m][n] = __builtin_amdgcn_mfma_f32_16x16x32_bf16(af[m], bfr[n], acc[m][n], 0, 0, 0);
    __builtin_amdgcn_s_setprio(0);
  };

  stage(0, 0);
  stage(1, 1);
  for (int kt = 0; kt < NKT; ++kt) {
    // vmcnt is FIFO-ordered: this also drains the warming loads on kt=0.
    if (kt == NKT - 1) asm volatile("s_waitcnt vmcnt(0)" ::: "memory");
    else               asm volatile("s_waitcnt vmcnt(3)" ::: "memory");
    __builtin_amdgcn_s_barrier();
    __builtin_amdgcn_sched_barrier(0);
    if (kt + 2 < NKT) stage((kt + 2) % 3, kt + 2);
    compute(kt % 3);
  }

  // ---- epilogue: BCE terms. C/D: col(i) = lane&15, row(j) = (lane>>4)*4 + reg ----
  u64 ki[4];
#pragma unroll
  for (int n = 0; n < 4; ++n)
    ki[n] = keys[ib + wc * 64 + n * 16 + lr];

  float sum = 0.f;
#pragma unroll
  for (int m = 0; m < 4; ++m)
#pragma unroll
    for (int r = 0; r < 4; ++r) {
      const u64 kj = keys[jb + wr * 64 + m * 16 + kq * 4 + r];
#pragma unroll
      for (int n = 0; n < 4; ++n) {
        const float p = acc[m][n][r];
        const bool  t = (kj == ki[n]);
        const float xx = t ? p : (1.0f - p);
        sum += fmaxf(__logf(xx), -100.0f);
      }
    }

  __syncthreads();              // warming scribbles + K-loop done before red reuse
  red[tid] = sum;
  __syncthreads();
#pragma unroll
  for (int s = 256; s > 0; s >>= 1) {
    if (tid < s) red[tid] += red[tid + s];
    __syncthreads();
  }
  if (tid == 0) {
    partials[bid] = red[0];
    __threadfence();                                   // partial visible device-wide
    lastflag = (atomicAdd(counter, 1u) == NBLK - 1u);  // device-scope
    if (lastflag) __threadfence();                     // acquire all partials
  }
  __syncthreads();
  if (lastflag) {                                      // one block sums in fixed order
    red[tid] = partials[tid];
    __syncthreads();
#pragma unroll
    for (int s = 256; s > 0; s >>= 1) {
      if (tid < s) red[tid] += red[tid + s];
      __syncthreads();
    }
    if (tid == 0) out[0] = -red[0] * (1.0f / 16777216.0f);  // -mean over N^2
  }
}

extern "C" void kernel_launch(void* const* d_in, const int* in_sizes, int n_in,
                              void* d_out, int out_size, void* d_ws, size_t ws_size,
                              hipStream_t stream) {
  (void)in_sizes; (void)n_in; (void)out_size; (void)ws_size;
  const float* feat1 = (const float*)d_in[0];
  const float* prob1 = (const float*)d_in[2];
  const float* prob2 = (const float*)d_in[3];

  // ws: o1 bf16 (4MB) | o2 bf16 (4MB) | keys (32KB) | partials (2KB) | counter (4B)
  __bf16* o1 = (__bf16*)d_ws;
  __bf16* o2 = (__bf16*)((char*)d_ws + (size_t)NROWS * CDIM * 2);
  u64*   keys = (u64*)((char*)d_ws + (size_t)NROWS * CDIM * 4);
  float* partials = (float*)((char*)d_ws + (size_t)NROWS * CDIM * 4 + NROWS * 8);
  unsigned* counter = (unsigned*)((char*)d_ws + (size_t)NROWS * CDIM * 4 + NROWS * 8 + NBLK * 4);

  prep_kernel<<<3072, 256, 0, stream>>>(prob1, prob2, feat1, o1, o2, keys, counter);
  gemm_loss_kernel<<<NBLK, 512, 0, stream>>>(o1, o2, keys, partials, counter, (float*)d_out);
}

// Round 12
// 41.857 us; speedup vs baseline: 1.6263x; 1.6263x over previous
//
#include <hip/hip_runtime.h>
#include <hip/hip_bf16.h>
#include <stdint.h>

#define NROWS 4096
#define CDIM  512
#define TOPK  5
#define BMJ   128   // prob2 (j) rows per block
#define BNI   256   // prob1 (i) rows per block
#define BK    64    // K per step (fp8: 64 elems = 64 B/row)
#define NKT   8     // CDIM / BK
#define NBLK  512   // gemm grid
#define PSCALE 256.0f             // pre-scale: lifts probs out of e4m3 denormal range
#define PSCALE_INV (1.0f / 65536.0f)   // 1 / PSCALE^2

typedef float f32x4 __attribute__((ext_vector_type(4)));
typedef long  lx2   __attribute__((ext_vector_type(2)));
typedef unsigned long long u64;
typedef unsigned char u8;

// 16B-granule swizzle: 16-lane b128 fragment reads land 2 lanes/bank-granule (free)
__device__ __forceinline__ int swz2(int r) { return ((r >> 1) ^ (r >> 3)) & 3; }

// fp8 row layout (64 B per row per kt): logical granule g (0..3) holds
// k in [g*8, g*8+8) at bytes 0-7 (lo) and k in [32+g*8, 32+g*8+8) at bytes 8-15 (hi).
// Physical granule = g ^ swz2(row). One ds_read_b128 yields {lo8 | hi8} = the two
// K=32 operands of the 16x16x32 fp8 MFMA pair.

// ---------------- kernel A: prep = f32 -> fp8 e4m3 convert (x256) + top-5 keys ----------------
__global__ __launch_bounds__(256) void
prep_kernel(const float* __restrict__ p1, const float* __restrict__ p2,
            const float* __restrict__ feat1,
            u8* __restrict__ o1, u8* __restrict__ o2,
            u64* __restrict__ keys, unsigned* __restrict__ counter) {
  const int bid = blockIdx.x, tid = threadIdx.x;
  if (bid == 0 && tid == 0) *counter = 0;   // for gemm's last-block finalize
  if (bid < 2048) {
    const int t   = bid * 256 + tid;        // 0..524287
    const int arr = t >> 18;                // 0: p1->o1, 1: p2->o2
    const int e   = t & 262143;             // 8 elems each
    const int row = e >> 6;
    const int k8  = e & 63;                 // 8-elem group within the row
    const int kt  = k8 >> 3;                // K-tile
    const int kk  = k8 & 7;                 // 8-elem group within K-tile
    const int g   = kk & 3;                 // logical granule
    const int h   = kk >> 2;                // 0 = lo-K half, 1 = hi-K half
    const int pg  = g ^ swz2(row);          // physical granule
    const float* src = (arr ? p2 : p1) + (size_t)row * CDIM + kt * 64 + kk * 8;
    u8* dst = (arr ? o2 : o1) + ((size_t)kt * NROWS + row) * 64 + pg * 16 + h * 8;
    const f32x4 a = *(const f32x4*)src;
    const f32x4 b = *(const f32x4*)(src + 4);
    unsigned lo = __builtin_amdgcn_cvt_pk_fp8_f32(a[0] * PSCALE, a[1] * PSCALE, 0, false);
    lo = __builtin_amdgcn_cvt_pk_fp8_f32(a[2] * PSCALE, a[3] * PSCALE, lo, true);
    unsigned hi = __builtin_amdgcn_cvt_pk_fp8_f32(b[0] * PSCALE, b[1] * PSCALE, 0, false);
    hi = __builtin_amdgcn_cvt_pk_fp8_f32(b[2] * PSCALE, b[3] * PSCALE, hi, true);
    ((unsigned*)dst)[0] = lo;
    ((unsigned*)dst)[1] = hi;
  } else {
    const int row = (bid - 2048) * 4 + (tid >> 6);
    const int l   = tid & 63;
    const float* r = feat1 + (size_t)row * CDIM;
    float v[8];
    const float4 a = *(const float4*)(r + l * 8);
    const float4 b = *(const float4*)(r + l * 8 + 4);
    v[0]=a.x; v[1]=a.y; v[2]=a.z; v[3]=a.w;
    v[4]=b.x; v[5]=b.y; v[6]=b.z; v[7]=b.w;

    int sel[TOPK];
#pragma unroll
    for (int s = 0; s < TOPK; ++s) {
      float bv = -__builtin_inff();
      int   bi = 0x7fffffff;
#pragma unroll
      for (int t2 = 0; t2 < 8; ++t2)
        if (v[t2] > bv) { bv = v[t2]; bi = l * 8 + t2; }  // strict > : smallest idx on tie
#pragma unroll
      for (int off = 32; off > 0; off >>= 1) {
        float ov = __shfl_xor(bv, off);
        int   oi = __shfl_xor(bi, off);
        if (ov > bv || (ov == bv && oi < bi)) { bv = ov; bi = oi; }
      }
      sel[s] = bi;
      const int loc = bi - l * 8;
      if (loc >= 0 && loc < 8) v[loc] = -__builtin_inff();
    }
#define CSWAP(x, y) { int mn = min(sel[x], sel[y]); int mx = max(sel[x], sel[y]); sel[x] = mn; sel[y] = mx; }
    CSWAP(0,1) CSWAP(3,4) CSWAP(2,4) CSWAP(2,3) CSWAP(1,4)
    CSWAP(0,3) CSWAP(0,2) CSWAP(1,3) CSWAP(1,2)
#undef CSWAP
    if (l == 0) {
      keys[row] = (u64)sel[0] | ((u64)sel[1] << 9) | ((u64)sel[2] << 18)
                | ((u64)sel[3] << 27) | ((u64)sel[4] << 36);
    }
  }
}

// ---------------- kernel B: fp8 GEMM + BCE + last-block finalize ----------------
// R4 skeleton: 128(j) x 256(i) tile, 512 thr = 8 waves (2x4), per-wave 64x64 =
// acc[4][4]. BK=64: 32 MFMA + 8 ds_read_b128 per wave per step (reads/MFMA = 0.25).
// 3-slot LDS rotation (72 KiB -> 2 blocks/CU), depth-2 counted vmcnt(3) whose
// lead time spans 32 MFMA (~1240 cyc) - covers L3 latency on sweep 1.
__global__ __launch_bounds__(512, 4) void
gemm_loss_kernel(const u8* __restrict__ o1k,   // prob1 (i), [kt][row][64B]
                 const u8* __restrict__ o2k,   // prob2 (j), [kt][row][64B]
                 const u64* __restrict__ keys,
                 float* __restrict__ partials,
                 unsigned* __restrict__ counter,
                 float* __restrict__ out) {
  __shared__ u8 smA[3][BMJ * BK];   // 3 x 8 KB  (prob2 / j)
  __shared__ u8 smB[3][BNI * BK];   // 3 x 16 KB (prob1 / i)
  __shared__ float red[512];
  __shared__ int   lastflag;

  const int tid = threadIdx.x;
  const int l   = tid & 63, w = tid >> 6;
  const int wr  = w >> 2,  wc = w & 3;     // j-half, i-quarter
  const int lr  = l & 15,  kq = l >> 4;

  const int bid = blockIdx.x;
  const int x   = bid & 7, v = bid >> 3;   // XCD-chunked swizzle
  const int jt  = (x & 3) * 8 + (v & 7);
  const int it  = (x >> 2) * 8 + (v >> 3);
  const int jb  = jt * BMJ, ib = it * BNI;

  f32x4 acc[4][4] = {};

  const u8* gA0 = o2k + (size_t)jb * 64;
  const u8* gB0 = o1k + (size_t)ib * 64;

  auto stage = [&](int slot, int kt) {   // 3 x 16B loads per thread
    const size_t ko = (size_t)kt * NROWS * 64;
    __builtin_amdgcn_global_load_lds(
        (const __attribute__((address_space(1))) unsigned int*)(const void*)(gA0 + ko + tid * 16),
        (__attribute__((address_space(3))) unsigned int*)(void*)&smA[slot][w * 1024], 16, 0, 0);
#pragma unroll
    for (int i = 0; i < 2; ++i) {
      __builtin_amdgcn_global_load_lds(
          (const __attribute__((address_space(1))) unsigned int*)(const void*)(gB0 + ko + (i * 512 + tid) * 16),
          (__attribute__((address_space(3))) unsigned int*)(void*)&smB[slot][i * 8192 + w * 1024], 16, 0, 0);
    }
  };

  auto compute = [&](int slot) {
    lx2 af[4], bfr[4];
#pragma unroll
    for (int m = 0; m < 4; ++m) {
      const int r = wr * 64 + m * 16 + lr;           // 0..127
      af[m] = *(const lx2*)&smA[slot][r * 64 + ((kq ^ swz2(r)) << 4)];
    }
#pragma unroll
    for (int n = 0; n < 4; ++n) {
      const int r = wc * 64 + n * 16 + lr;           // 0..255
      bfr[n] = *(const lx2*)&smB[slot][r * 64 + ((kq ^ swz2(r)) << 4)];
    }
    __builtin_amdgcn_s_setprio(1);
#pragma unroll
    for (int m = 0; m < 4; ++m)
#pragma unroll
      for (int n = 0; n < 4; ++n) {
        acc[m][n] = __builtin_amdgcn_mfma_f32_16x16x32_fp8_fp8(af[m][0], bfr[n][0], acc[m][n], 0, 0, 0);
        acc[m][n] = __builtin_amdgcn_mfma_f32_16x16x32_fp8_fp8(af[m][1], bfr[n][1], acc[m][n], 0, 0, 0);
      }
    __builtin_amdgcn_s_setprio(0);
  };

  stage(0, 0);
  stage(1, 1);
  for (int kt = 0; kt < NKT; ++kt) {
    if (kt == NKT - 1) asm volatile("s_waitcnt vmcnt(0)" ::: "memory");
    else               asm volatile("s_waitcnt vmcnt(3)" ::: "memory");  // own kt-loads landed
    __builtin_amdgcn_s_barrier();
    __builtin_amdgcn_sched_barrier(0);
    if (kt + 2 < NKT) stage((kt + 2) % 3, kt + 2);
    compute(kt % 3);
  }

  // ---- epilogue: BCE terms, acc scaled by PSCALE^2. C/D: col=lane&15, row=(lane>>4)*4+reg ----
  u64 ki[4];
#pragma unroll
  for (int n = 0; n < 4; ++n)
    ki[n] = keys[ib + wc * 64 + n * 16 + lr];

  float sum = 0.f;
#pragma unroll
  for (int m = 0; m < 4; ++m)
#pragma unroll
    for (int r = 0; r < 4; ++r) {
      const u64 kj = keys[jb + wr * 64 + m * 16 + kq * 4 + r];
#pragma unroll
      for (int n = 0; n < 4; ++n) {
        const float p = acc[m][n][r] * PSCALE_INV;
        const bool  t = (kj == ki[n]);
        const float xx = t ? p : (1.0f - p);
        sum += fmaxf(__logf(xx), -100.0f);
      }
    }

  red[tid] = sum;
  __syncthreads();
#pragma unroll
  for (int s = 256; s > 0; s >>= 1) {
    if (tid < s) red[tid] += red[tid + s];
    __syncthreads();
  }
  if (tid == 0) {
    partials[bid] = red[0];
    __threadfence();                                   // partial visible device-wide
    lastflag = (atomicAdd(counter, 1u) == NBLK - 1u);  // device-scope
    if (lastflag) __threadfence();                     // acquire all partials
  }
  __syncthreads();
  if (lastflag) {                                      // one block sums in fixed order
    red[tid] = partials[tid];
    __syncthreads();
#pragma unroll
    for (int s = 256; s > 0; s >>= 1) {
      if (tid < s) red[tid] += red[tid + s];
      __syncthreads();
    }
    if (tid == 0) out[0] = -red[0] * (1.0f / 16777216.0f);  // -mean over N^2
  }
}

extern "C" void kernel_launch(void* const* d_in, const int* in_sizes, int n_in,
                              void* d_out, int out_size, void* d_ws, size_t ws_size,
                              hipStream_t stream) {
  (void)in_sizes; (void)n_in; (void)out_size; (void)ws_size;
  const float* feat1 = (const float*)d_in[0];
  const float* prob1 = (const float*)d_in[2];
  const float* prob2 = (const float*)d_in[3];

  // ws: o1 fp8 (2MB) | o2 fp8 (2MB) | keys (32KB) | partials (2KB) | counter (4B)
  u8* o1 = (u8*)d_ws;
  u8* o2 = (u8*)d_ws + (size_t)NROWS * CDIM;
  u64*   keys = (u64*)((char*)d_ws + (size_t)NROWS * CDIM * 2);
  float* partials = (float*)((char*)d_ws + (size_t)NROWS * CDIM * 2 + NROWS * 8);
  unsigned* counter = (unsigned*)((char*)d_ws + (size_t)NROWS * CDIM * 2 + NROWS * 8 + NBLK * 4);

  prep_kernel<<<3072, 256, 0, stream>>>(prob1, prob2, feat1, o1, o2, keys, counter);
  gemm_loss_kernel<<<NBLK, 512, 0, stream>>>(o1, o2, keys, partials, counter, (float*)d_out);
}